// Round 4
// baseline (7907.265 us; speedup 1.0000x reference)
//
#include <hip/hip_runtime.h>

typedef unsigned short u16;
typedef __attribute__((ext_vector_type(8))) short short8;
typedef __attribute__((ext_vector_type(4))) short short4v;
typedef __attribute__((ext_vector_type(4))) float f32x4;

#define NSTEP 24
#define NB 256

__device__ __forceinline__ float b2f(u16 u){ return __uint_as_float(((unsigned)u)<<16); }
__device__ __forceinline__ u16 f2b(float f){
  unsigned u = __float_as_uint(f);
  u += 0x7fffu + ((u>>16)&1u);
  return (u16)(u>>16);
}
__device__ __forceinline__ float tanh_fast(float x){
  x = fminf(12.f, fmaxf(-12.f, x));
  float e = __expf(2.f*x);
  return __fdividef(e-1.f, e+1.f);
}
__device__ __forceinline__ float sigmoid_fast(float x){
  return __fdividef(1.f, 1.f + __expf(-x));
}

// device-wide barrier: monotonic ticket counter, agent-scope fences.
// grid must be co-resident (256 blocks on 256 CUs -> guaranteed).
__device__ __forceinline__ void gbar(unsigned* bar){
  __syncthreads();                      // drains this block's stores to L2
  if (threadIdx.x == 0){
    __threadfence();                    // release: write-back L2 device-wide
    unsigned ticket = __hip_atomic_fetch_add(bar, 1u, __ATOMIC_RELAXED, __HIP_MEMORY_SCOPE_AGENT);
    unsigned target = (ticket/NB + 1u)*NB;
    while (__hip_atomic_load(bar, __ATOMIC_RELAXED, __HIP_MEMORY_SCOPE_AGENT) < target)
      __builtin_amdgcn_s_sleep(2);
  }
  __syncthreads();
  __threadfence();                      // acquire: invalidate caches in every wave
}

// ---------------- f32 -> bf16 bulk convert ----------------
__global__ __launch_bounds__(256) void k_cvt(const float* __restrict__ in, u16* __restrict__ out, int n){
  int i = (blockIdx.x*256 + threadIdx.x)*4;
  if (i >= n) return;
  float4 v = *(const float4*)(in + i);
  short4v o;
  o[0] = (short)f2b(v.x); o[1] = (short)f2b(v.y); o[2] = (short)f2b(v.z); o[3] = (short)f2b(v.w);
  *(short4v*)(out + i) = o;
}

// ---------------- transpose 512x512, f32 in -> bf16 out ----------------
__global__ __launch_bounds__(256) void k_transpose512(const float* __restrict__ in, u16* __restrict__ out){
  __shared__ float tile[32][33];
  int tx = threadIdx.x, ty = threadIdx.y;
  int x = blockIdx.x*32 + tx;
  #pragma unroll
  for (int j=0;j<4;++j){
    int y = blockIdx.y*32 + ty + j*8;
    tile[ty+j*8][tx] = in[y*512 + x];
  }
  __syncthreads();
  int x2 = blockIdx.y*32 + tx;
  #pragma unroll
  for (int j=0;j<4;++j){
    int y2 = blockIdx.x*32 + ty + j*8;
    out[y2*512 + x2] = f2b(tile[tx][ty+j*8]);
  }
}

// ---------------- init h ----------------
__global__ __launch_bounds__(256) void k_init(const float* __restrict__ h0, float* __restrict__ hf, u16* __restrict__ xcat){
  int idx = blockIdx.x*256 + threadIdx.x;     // < 32768
  float v = h0[idx];
  hf[idx] = v;
  xcat[(idx>>9)*1024 + 512 + (idx&511)] = f2b(v);
}

// ---------------- enc_proj = encB @ WeT^T  (MFMA), bf16 out ----------------
__global__ __launch_bounds__(256) void k_encproj(const u16* __restrict__ A, const u16* __restrict__ BT, u16* __restrict__ C){
  int w = threadIdx.x>>6, lane = threadIdx.x&63;
  int m0 = blockIdx.x*128 + (w>>1)*64;
  int n0 = blockIdx.y*128 + (w&1)*64;
  int r16 = lane&15, kof = (lane>>4)<<3;
  const u16* Ap = A + (m0+r16)*512 + kof;
  const u16* Bp = BT + (n0+r16)*512 + kof;
  f32x4 acc[4][4];
  #pragma unroll
  for (int i=0;i<4;++i)
    #pragma unroll
    for (int j=0;j<4;++j) acc[i][j] = (f32x4){0.f,0.f,0.f,0.f};
  for (int k0=0;k0<512;k0+=32){
    short8 a[4], b[4];
    #pragma unroll
    for (int mf=0;mf<4;++mf) a[mf] = *(const short8*)(Ap + mf*16*512 + k0);
    #pragma unroll
    for (int nf=0;nf<4;++nf) b[nf] = *(const short8*)(Bp + nf*16*512 + k0);
    #pragma unroll
    for (int mf=0;mf<4;++mf)
      #pragma unroll
      for (int nf=0;nf<4;++nf)
        acc[mf][nf] = __builtin_amdgcn_mfma_f32_16x16x32_bf16(a[mf], b[nf], acc[mf][nf], 0,0,0);
  }
  int rb = (lane>>4)<<2;
  #pragma unroll
  for (int mf=0;mf<4;++mf)
    #pragma unroll
    for (int nf=0;nf<4;++nf)
      #pragma unroll
      for (int r=0;r<4;++r)
        C[(m0+mf*16+rb+r)*512 + n0+nf*16+r16] = f2b(acc[mf][nf][r]);
}

// ---------------- MFMA tile: C[16 x 64 at (mt,nt)] (+)= A(64 x K) @ BT^T ----------------
__device__ __forceinline__ void gemm_tile(const u16* A, int lda, const u16* BT, int ldb,
    const float* bias, float* C, int ldc, int K, int mt, int nt, bool accum){
  int lane = threadIdx.x & 63;
  int m0 = mt<<4, n0 = nt<<6;
  int r16 = lane&15, kof = (lane>>4)<<3;
  const u16* Ap = A + (m0+r16)*lda + kof;
  const u16* Bp = BT + (n0+r16)*ldb + kof;
  f32x4 acc[4];
  #pragma unroll
  for (int i=0;i<4;++i) acc[i] = (f32x4){0.f,0.f,0.f,0.f};
  for (int k0=0;k0<K;k0+=32){
    short8 a = *(const short8*)(Ap + k0);
    #pragma unroll
    for (int nf=0;nf<4;++nf){
      short8 b = *(const short8*)(Bp + nf*16*ldb + k0);
      acc[nf] = __builtin_amdgcn_mfma_f32_16x16x32_bf16(a, b, acc[nf], 0,0,0);
    }
  }
  int rb = (lane>>4)<<2;
  #pragma unroll
  for (int nf=0;nf<4;++nf){
    int col = n0 + nf*16 + r16;
    float bv = bias ? bias[col] : 0.f;
    #pragma unroll
    for (int r=0;r<4;++r){
      float* p = &C[(m0+rb+r)*ldc + col];
      float v = acc[nf][r] + bv;
      if (accum) v += *p;
      *p = v;
    }
  }
}

// ---------------- q[j] = ab[j] + sum_k hl[k]*WdT[j][k], 2 outputs per thread ----------------
__device__ __forceinline__ void q_core(const float* hl, const u16* WdT, const float* ab, float* qrow){
  int tid = threadIdx.x;
  #pragma unroll
  for (int jj=0;jj<2;++jj){
    int j = tid + jj*256;
    float acc = ab[j];
    const u16* wr = WdT + j*512;
    #pragma unroll 4
    for (int k0=0;k0<512;k0+=8){
      short8 wv = *(const short8*)(wr + k0);
      #pragma unroll
      for (int i=0;i<8;++i) acc = fmaf(hl[k0+i], b2f((u16)wv[i]), acc);
    }
    qrow[j] = acc;
  }
}

// ---------------- persistent 24-step decoder ----------------
__global__ __launch_bounds__(256) void k_steps(
    const u16* __restrict__ ep, const u16* __restrict__ encB,
    const u16* __restrict__ WdT, const u16* __restrict__ WihB, const u16* __restrict__ WhhB,
    const float* __restrict__ ab, const float* __restrict__ av,
    const float* __restrict__ bih, const float* __restrict__ bhh,
    const float* __restrict__ lng, const float* __restrict__ lnb,
    const float* __restrict__ W1, const float* __restrict__ b1,
    const float* __restrict__ W2, const float* __restrict__ b2,
    float* __restrict__ hf, u16* __restrict__ xcat, float* __restrict__ q,
    float* __restrict__ sc, float* __restrict__ gi, float* __restrict__ gh,
    float* __restrict__ out, unsigned* __restrict__ bar)
{
  __shared__ float sm[2816];   // P2: red[256] al[512] part[2048]; P4: hl[512] yn[512] red[256]
  int tid = threadIdx.x, bid = blockIdx.x;
  int wid = tid>>6, lane = tid&63;

  // persistent per-lane v fragment for P1
  float vv[8];
  {
    float4 v0 = *(const float4*)(av + lane*8);
    float4 v1 = *(const float4*)(av + lane*8 + 4);
    vv[0]=v0.x; vv[1]=v0.y; vv[2]=v0.z; vv[3]=v0.w;
    vv[4]=v1.x; vv[5]=v1.y; vv[6]=v1.z; vv[7]=v1.w;
  }

  // prologue: q(0) from h0
  if (bid < 64){
    float* hl = sm;
    hl[tid] = hf[bid*512 + tid];
    hl[tid+256] = hf[bid*512 + 256 + tid];
    __syncthreads();
    q_core(hl, WdT, ab, q + bid*512);
  }
  gbar(bar);

  for (int t=0; t<NSTEP; ++t){
    // ---- P1: scores. block = (b, s-quarter); wave covers 32 s-rows ----
    {
      int b = bid>>2;
      float qv[8];
      {
        float4 q0 = *(const float4*)(q + b*512 + lane*8);
        float4 q1 = *(const float4*)(q + b*512 + lane*8 + 4);
        qv[0]=q0.x; qv[1]=q0.y; qv[2]=q0.z; qv[3]=q0.w;
        qv[4]=q1.x; qv[5]=q1.y; qv[6]=q1.z; qv[7]=q1.w;
      }
      int srow0 = (bid&3)*128 + wid*32;
      const u16* eprow = ep + (b*512 + srow0)*512 + lane*8;
      #pragma unroll 2
      for (int i=0;i<32;++i){
        short8 e = *(const short8*)(eprow + i*512);
        float acc = 0.f;
        #pragma unroll
        for (int j=0;j<8;++j)
          acc += vv[j]*tanh_fast(b2f((u16)e[j]) + qv[j]);
        #pragma unroll
        for (int off=32; off; off>>=1) acc += __shfl_xor(acc, off);
        if (lane==0) sc[b*512 + srow0 + i] = acc;
      }
    }
    gbar(bar);

    // ---- P2: softmax+context (0..63) || gh GEMM (64..87) || gi h-half GEMM (88..111) ----
    if (bid < 64){
      float* red = sm;
      float* al  = sm + 256;
      float* part= sm + 768;
      int b = bid;
      float s1 = sc[b*512 + tid], s2 = sc[b*512 + 256 + tid];
      red[tid] = fmaxf(s1, s2); __syncthreads();
      for (int off=128; off; off>>=1){ if (tid<off) red[tid] = fmaxf(red[tid], red[tid+off]); __syncthreads(); }
      float mx = red[0]; __syncthreads();
      float e1 = __expf(s1-mx), e2 = __expf(s2-mx);
      red[tid] = e1+e2; __syncthreads();
      for (int off=128; off; off>>=1){ if (tid<off) red[tid] += red[tid+off]; __syncthreads(); }
      float inv = __fdividef(1.f, red[0]);
      al[tid] = e1*inv; al[tid+256] = e2*inv;
      __syncthreads();
      int hg = (tid&63)*8, sch = tid>>6;
      float a8[8];
      #pragma unroll
      for (int j=0;j<8;++j) a8[j] = 0.f;
      const u16* eb = encB + (b*512 + sch*128)*512 + hg;
      const float* alp = al + sch*128;
      for (int s=0;s<128;++s){
        short8 e = *(const short8*)(eb + s*512);
        float a = alp[s];
        #pragma unroll
        for (int j=0;j<8;++j) a8[j] = fmaf(a, b2f((u16)e[j]), a8[j]);
      }
      #pragma unroll
      for (int j=0;j<8;++j) part[sch*512 + hg+j] = a8[j];
      __syncthreads();
      for (int h=tid; h<512; h+=256){
        float v = part[h] + part[512+h] + part[1024+h] + part[1536+h];
        xcat[b*1024 + h] = f2b(v);
      }
    } else if (bid < 88){
      int w = (bid-64)*4 + wid;       // 96 waves: gh = h @ WhhB^T + bhh
      gemm_tile(xcat+512, 1024, WhhB, 512, bhh, gh, 1536, 512, w&3, w>>2, false);
    } else if (bid < 112){
      int w = (bid-88)*4 + wid;       // 96 waves: gi_h = h @ Wih[:,512:]^T + bih
      gemm_tile(xcat+512, 1024, WihB+512, 1024, bih, gi, 1536, 512, w&3, w>>2, false);
    }
    gbar(bar);

    // ---- P3: gi += ctx @ Wih[:,:512]^T ----
    if (bid < 24){
      int w = bid*4 + wid;
      gemm_tile(xcat, 1024, WihB, 1024, (const float*)0, gi, 1536, 512, w&3, w>>2, true);
    }
    gbar(bar);

    // ---- P4: gates + head + next q, per-b ----
    if (bid < 64){
      int b = bid;
      float* hl  = sm;
      float* yn  = sm + 512;
      float* red = sm + 1024;
      #pragma unroll
      for (int jj=0;jj<2;++jj){
        int n = tid + jj*256;
        int gb = b*1536 + n;
        float r  = sigmoid_fast(gi[gb]      + gh[gb]);
        float z  = sigmoid_fast(gi[gb+512]  + gh[gb+512]);
        float nn = tanh_fast(gi[gb+1024] + r*gh[gb+1024]);
        float hp = hf[b*512 + n];
        float hnew = (1.f-z)*nn + z*hp;
        hf[b*512 + n] = hnew;
        xcat[b*1024 + 512 + n] = f2b(hnew);
        hl[n] = hnew;
        if (t == NSTEP-1) out[1536 + b*512 + n] = hnew;
      }
      __syncthreads();
      float h1 = hl[tid], h2 = hl[tid+256];
      red[tid] = h1+h2; __syncthreads();
      for (int off=128; off; off>>=1){ if (tid<off) red[tid]+=red[tid+off]; __syncthreads(); }
      float mu = red[0]*(1.f/512.f); __syncthreads();
      red[tid] = h1*h1+h2*h2; __syncthreads();
      for (int off=128; off; off>>=1){ if (tid<off) red[tid]+=red[tid+off]; __syncthreads(); }
      float var = red[0]*(1.f/512.f) - mu*mu; __syncthreads();
      float rs = rsqrtf(var + 1e-5f);
      yn[tid]     = (h1-mu)*rs*lng[tid] + lnb[tid];
      yn[tid+256] = (h2-mu)*rs*lng[tid+256] + lnb[tid+256];
      __syncthreads();
      float acc = b1[tid];
      #pragma unroll 8
      for (int k=0;k<512;++k) acc = fmaf(yn[k], W1[k*256+tid], acc);
      float y = fmaxf(acc, 0.f);
      red[tid] = y*W2[tid]; __syncthreads();
      for (int off=128; off; off>>=1){ if (tid<off) red[tid]+=red[tid+off]; __syncthreads(); }
      if (tid==0) out[b*24 + t] = red[0] + b2[0];
      if (t < NSTEP-1){
        __syncthreads();
        q_core(hl, WdT, ab, q + b*512);   // hl still holds h_new
      }
    }
    gbar(bar);
  }
}

extern "C" void kernel_launch(void* const* d_in, const int* in_sizes, int n_in,
                              void* d_out, int out_size, void* d_ws, size_t ws_size,
                              hipStream_t stream){
  (void)in_sizes; (void)n_in; (void)out_size; (void)ws_size;
  const float* enc = (const float*)d_in[0];
  const float* h0  = (const float*)d_in[1];
  const float* We  = (const float*)d_in[2];
  const float* Wd  = (const float*)d_in[3];
  const float* ab  = (const float*)d_in[4];
  const float* av  = (const float*)d_in[5];
  const float* Wih = (const float*)d_in[6];
  const float* Whh = (const float*)d_in[7];
  const float* bih = (const float*)d_in[8];
  const float* bhh = (const float*)d_in[9];
  const float* lng = (const float*)d_in[10];
  const float* lnb = (const float*)d_in[11];
  const float* W1  = (const float*)d_in[12];
  const float* b1  = (const float*)d_in[13];
  const float* W2  = (const float*)d_in[14];
  const float* b2  = (const float*)d_in[15];
  float* out = (float*)d_out;
  char* ws = (char*)d_ws;
  u16*  ep   = (u16*)(ws + 0);          // 33,554,432
  u16*  encB = (u16*)(ws + 33554432);   // 33,554,432
  u16*  WeT  = (u16*)(ws + 67108864);   //    524,288  (dead after k_encproj; barrier counter lives here)
  u16*  WdT  = (u16*)(ws + 67633152);   //    524,288
  u16*  WihB = (u16*)(ws + 68157440);   //  3,145,728
  u16*  WhhB = (u16*)(ws + 71303168);   //  1,572,864
  float* hf  = (float*)(ws + 72876032); //    131,072
  u16*  xcat = (u16*)(ws + 73007104);   //    131,072  [ctx(512); h(512)] bf16 per b
  float* q   = (float*)(ws + 73138176); //    131,072
  float* sc  = (float*)(ws + 73269248); //    131,072
  float* gi  = (float*)(ws + 73400320); //    393,216
  float* gh  = (float*)(ws + 73793536); //    393,216  -> total ~70.8 MB
  unsigned* bar = (unsigned*)WeT;

  k_cvt<<<16384, 256, 0, stream>>>(enc, encB, 16777216);
  k_cvt<<<1536, 256, 0, stream>>>(Wih, WihB, 1572864);
  k_cvt<<<768, 256, 0, stream>>>(Whh, WhhB, 786432);
  k_transpose512<<<dim3(16,16), dim3(32,8), 0, stream>>>(We, WeT);
  k_transpose512<<<dim3(16,16), dim3(32,8), 0, stream>>>(Wd, WdT);
  k_init<<<128, 256, 0, stream>>>(h0, hf, xcat);
  k_encproj<<<dim3(256,4), 256, 0, stream>>>(encB, WeT, ep);
  hipMemsetAsync(bar, 0, 64, stream);   // WeT dead from here on
  k_steps<<<NB, 256, 0, stream>>>(ep, encB, WdT, WihB, WhhB, ab, av, bih, bhh,
                                  lng, lnb, W1, b1, W2, b2,
                                  hf, xcat, q, sc, gi, gh, out, (unsigned*)bar);
}

// Round 5
// 2163.783 us; speedup vs baseline: 3.6544x; 3.6544x over previous
//
#include <hip/hip_runtime.h>

typedef unsigned short u16;
typedef __attribute__((ext_vector_type(8))) short short8;
typedef __attribute__((ext_vector_type(4))) short short4v;
typedef __attribute__((ext_vector_type(4))) float f32x4;

#define NSTEP 24

__device__ __forceinline__ float b2f(u16 u){ return __uint_as_float(((unsigned)u)<<16); }
__device__ __forceinline__ u16 f2b(float f){
  unsigned u = __float_as_uint(f);
  u += 0x7fffu + ((u>>16)&1u);
  return (u16)(u>>16);
}
__device__ __forceinline__ float tanh_fast(float x){
  x = fminf(12.f, fmaxf(-12.f, x));
  float e = __expf(2.f*x);
  return __fdividef(e-1.f, e+1.f);
}
__device__ __forceinline__ float sigmoid_fast(float x){
  return __fdividef(1.f, 1.f + __expf(-x));
}

// ---------------- f32 -> bf16 bulk convert ----------------
__global__ __launch_bounds__(256) void k_cvt(const float* __restrict__ in, u16* __restrict__ out, int n){
  int i = (blockIdx.x*256 + threadIdx.x)*4;
  if (i >= n) return;
  float4 v = *(const float4*)(in + i);
  short4v o;
  o[0] = (short)f2b(v.x); o[1] = (short)f2b(v.y); o[2] = (short)f2b(v.z); o[3] = (short)f2b(v.w);
  *(short4v*)(out + i) = o;
}

// ---------------- transpose 512x512, f32 in -> bf16 out ----------------
__global__ __launch_bounds__(256) void k_transpose512(const float* __restrict__ in, u16* __restrict__ out){
  __shared__ float tile[32][33];
  int tx = threadIdx.x, ty = threadIdx.y;
  int x = blockIdx.x*32 + tx;
  #pragma unroll
  for (int j=0;j<4;++j){
    int y = blockIdx.y*32 + ty + j*8;
    tile[ty+j*8][tx] = in[y*512 + x];
  }
  __syncthreads();
  int x2 = blockIdx.y*32 + tx;
  #pragma unroll
  for (int j=0;j<4;++j){
    int y2 = blockIdx.x*32 + ty + j*8;
    out[y2*512 + x2] = f2b(tile[tx][ty+j*8]);
  }
}

// ---------------- init h ----------------
__global__ __launch_bounds__(256) void k_init(const float* __restrict__ h0, float* __restrict__ hf, u16* __restrict__ xcat){
  int idx = blockIdx.x*256 + threadIdx.x;     // < 32768
  float v = h0[idx];
  hf[idx] = v;
  xcat[(idx>>9)*1024 + 512 + (idx&511)] = f2b(v);
}

// ---------------- enc_proj = encB @ WeT^T  (MFMA), bf16 out ----------------
__global__ __launch_bounds__(256) void k_encproj(const u16* __restrict__ A, const u16* __restrict__ BT, u16* __restrict__ C){
  int w = threadIdx.x>>6, lane = threadIdx.x&63;
  int m0 = blockIdx.x*128 + (w>>1)*64;
  int n0 = blockIdx.y*128 + (w&1)*64;
  int r16 = lane&15, kof = (lane>>4)<<3;
  const u16* Ap = A + (m0+r16)*512 + kof;
  const u16* Bp = BT + (n0+r16)*512 + kof;
  f32x4 acc[4][4];
  #pragma unroll
  for (int i=0;i<4;++i)
    #pragma unroll
    for (int j=0;j<4;++j) acc[i][j] = (f32x4){0.f,0.f,0.f,0.f};
  for (int k0=0;k0<512;k0+=32){
    short8 a[4], b[4];
    #pragma unroll
    for (int mf=0;mf<4;++mf) a[mf] = *(const short8*)(Ap + mf*16*512 + k0);
    #pragma unroll
    for (int nf=0;nf<4;++nf) b[nf] = *(const short8*)(Bp + nf*16*512 + k0);
    #pragma unroll
    for (int mf=0;mf<4;++mf)
      #pragma unroll
      for (int nf=0;nf<4;++nf)
        acc[mf][nf] = __builtin_amdgcn_mfma_f32_16x16x32_bf16(a[mf], b[nf], acc[mf][nf], 0,0,0);
  }
  int rb = (lane>>4)<<2;
  #pragma unroll
  for (int mf=0;mf<4;++mf)
    #pragma unroll
    for (int nf=0;nf<4;++nf)
      #pragma unroll
      for (int r=0;r<4;++r)
        C[(m0+mf*16+rb+r)*512 + n0+nf*16+r16] = f2b(acc[mf][nf][r]);
}

// ---------------- small GEMM: C(64 x N) f32 = A(64 x K)bf16 @ BT(N x K)^T bf16 + bias f32 ----------------
__device__ __forceinline__ void gemm_bt_core(const u16* A, int lda, const u16* BT, int ldb,
    const float* bias, float* C, int ldc, int K, int widx){
  int lane = threadIdx.x & 63;
  int mt = widx & 3, nt = widx >> 2;
  int m0 = mt<<4, n0 = nt<<6;
  int r16 = lane&15, kof = (lane>>4)<<3;
  const u16* Ap = A + (m0+r16)*lda + kof;
  const u16* Bp = BT + (n0+r16)*ldb + kof;
  f32x4 acc[4];
  #pragma unroll
  for (int i=0;i<4;++i) acc[i] = (f32x4){0.f,0.f,0.f,0.f};
  for (int k0=0;k0<K;k0+=32){
    short8 a = *(const short8*)(Ap + k0);
    #pragma unroll
    for (int nf=0;nf<4;++nf){
      short8 b = *(const short8*)(Bp + nf*16*ldb + k0);
      acc[nf] = __builtin_amdgcn_mfma_f32_16x16x32_bf16(a, b, acc[nf], 0,0,0);
    }
  }
  int rb = (lane>>4)<<2;
  #pragma unroll
  for (int nf=0;nf<4;++nf){
    int col = n0 + nf*16 + r16;
    float bv = bias[col];
    #pragma unroll
    for (int r=0;r<4;++r)
      C[(m0+rb+r)*ldc + col] = acc[nf][r] + bv;
  }
}

// gi = xcat @ W_ih^T + b_ih (N=1536,K=1024); gh = h @ W_hh^T + b_hh (N=1536,K=512)
__global__ __launch_bounds__(256) void k_gru_gemm(const u16* __restrict__ xcat,
    const u16* __restrict__ Wih, const float* __restrict__ bih,
    const u16* __restrict__ Whh, const float* __restrict__ bhh,
    float* __restrict__ gi, float* __restrict__ gh){
  int widx = blockIdx.x*4 + (threadIdx.x>>6);
  if (blockIdx.y == 0)
    gemm_bt_core(xcat,       1024, Wih, 1024, bih, gi, 1536, 1024, widx);
  else
    gemm_bt_core(xcat + 512, 1024, Whh,  512, bhh, gh, 1536,  512, widx);
}

// ---------------- q[j] = ab[j] + sum_k hl[k]*WdT[j][k], 2 outputs per thread ----------------
__device__ __forceinline__ void q_core(const float* hl, const u16* WdT, const float* ab, float* qrow){
  int tid = threadIdx.x;
  #pragma unroll
  for (int jj=0;jj<2;++jj){
    int j = tid + jj*256;
    float acc = ab[j];
    const u16* wr = WdT + j*512;
    #pragma unroll 4
    for (int k0=0;k0<512;k0+=8){
      short8 wv = *(const short8*)(wr + k0);
      #pragma unroll
      for (int i=0;i<8;++i) acc = fmaf(hl[k0+i], b2f((u16)wv[i]), acc);
    }
    qrow[j] = acc;
  }
}

// ---------------- q(0) from h0 ----------------
__global__ __launch_bounds__(256) void k_q0(const float* __restrict__ hf, const u16* __restrict__ WdT,
    const float* __restrict__ ab, float* __restrict__ q){
  __shared__ float hl[512];
  int t = threadIdx.x, b = blockIdx.x;
  hl[t] = hf[b*512 + t];
  hl[t+256] = hf[b*512 + 256 + t];
  __syncthreads();
  q_core(hl, WdT, ab, q + b*512);
}

// ---------------- scores[b,s] = sum_h tanh(ep + q) * v ----------------
// grid (32, 64): 16 s-rows per block, 4 per wave.
__global__ __launch_bounds__(256) void k_score(const u16* __restrict__ ep, const float* __restrict__ q,
    const float* __restrict__ av, float* __restrict__ sc){
  __shared__ float qs[512], vs[512];
  int t = threadIdx.x, b = blockIdx.y;
  qs[t]     = q[b*512 + t];
  qs[t+256] = q[b*512 + 256 + t];
  vs[t]     = av[t];
  vs[t+256] = av[256 + t];
  __syncthreads();
  int w = t>>6, lane = t&63;
  float qv[8], vv[8];
  #pragma unroll
  for (int j=0;j<8;++j){ qv[j] = qs[lane*8+j]; vv[j] = vs[lane*8+j]; }
  int s0 = blockIdx.x*16 + w*4;
  #pragma unroll
  for (int i=0;i<4;++i){
    int s = s0 + i;
    short8 e = *(const short8*)(ep + (b*512+s)*512 + lane*8);
    float acc = 0.f;
    #pragma unroll
    for (int j=0;j<8;++j)
      acc += vv[j]*tanh_fast(b2f((u16)e[j]) + qv[j]);
    #pragma unroll
    for (int off=32; off; off>>=1) acc += __shfl_xor(acc, off);
    if (lane==0) sc[b*512 + s] = acc;
  }
}

// ---------------- softmax + context -> xcat[:, 0:512], one block per b, 512 thr ----------------
__global__ __launch_bounds__(512) void k_softctx(const float* __restrict__ sc, const u16* __restrict__ encB,
    u16* __restrict__ xcat){
  __shared__ float red[512];
  __shared__ float al[512];
  __shared__ float part[8][512];
  int t = threadIdx.x, b = blockIdx.x;
  float s1 = sc[b*512 + t];
  red[t] = s1; __syncthreads();
  for (int off=256; off; off>>=1){ if (t<off) red[t] = fmaxf(red[t], red[t+off]); __syncthreads(); }
  float mx = red[0]; __syncthreads();
  float e1 = __expf(s1-mx);
  red[t] = e1; __syncthreads();
  for (int off=256; off; off>>=1){ if (t<off) red[t] += red[t+off]; __syncthreads(); }
  float inv = __fdividef(1.f, red[0]);
  al[t] = e1*inv;
  __syncthreads();
  // wave w sums s in [w*64, w*64+64); lane covers h-cols [lane*8, lane*8+8)
  int lane = t&63, w = t>>6;
  int hg = lane*8;
  float a8[8];
  #pragma unroll
  for (int j=0;j<8;++j) a8[j] = 0.f;
  const u16* eb = encB + (b*512 + w*64)*512 + hg;
  const float* alp = al + w*64;
  for (int s=0;s<64;++s){
    short8 e = *(const short8*)(eb + s*512);
    float a = alp[s];
    #pragma unroll
    for (int j=0;j<8;++j) a8[j] = fmaf(a, b2f((u16)e[j]), a8[j]);
  }
  #pragma unroll
  for (int j=0;j<8;++j) part[w][hg+j] = a8[j];
  __syncthreads();
  float v = 0.f;
  #pragma unroll
  for (int w2=0;w2<8;++w2) v += part[w2][t];
  xcat[b*1024 + t] = f2b(v);
}

// ---------------- fin: gates + head + next q, one block per b ----------------
__global__ __launch_bounds__(256) void k_fin(const float* __restrict__ gi, const float* __restrict__ gh,
    const float* __restrict__ lng, const float* __restrict__ lnb,
    const float* __restrict__ W1, const float* __restrict__ b1,
    const float* __restrict__ W2, const float* __restrict__ b2,
    const u16* __restrict__ WdT, const float* __restrict__ ab,
    float* __restrict__ hf, u16* __restrict__ xcat, float* __restrict__ q,
    float* __restrict__ out, int step){
  __shared__ float hl[512];
  __shared__ float yn[512];
  __shared__ float red[256];
  int tid = threadIdx.x, b = blockIdx.x;
  #pragma unroll
  for (int jj=0;jj<2;++jj){
    int n = tid + jj*256;
    int gb = b*1536 + n;
    float r  = sigmoid_fast(gi[gb]      + gh[gb]);
    float z  = sigmoid_fast(gi[gb+512]  + gh[gb+512]);
    float nn = tanh_fast(gi[gb+1024] + r*gh[gb+1024]);
    float hp = hf[b*512 + n];
    float hnew = (1.f-z)*nn + z*hp;
    hf[b*512 + n] = hnew;
    xcat[b*1024 + 512 + n] = f2b(hnew);
    hl[n] = hnew;
    if (step == NSTEP-1) out[1536 + b*512 + n] = hnew;
  }
  __syncthreads();
  float h1 = hl[tid], h2 = hl[tid+256];
  red[tid] = h1+h2; __syncthreads();
  for (int off=128; off; off>>=1){ if (tid<off) red[tid]+=red[tid+off]; __syncthreads(); }
  float mu = red[0]*(1.f/512.f); __syncthreads();
  red[tid] = h1*h1+h2*h2; __syncthreads();
  for (int off=128; off; off>>=1){ if (tid<off) red[tid]+=red[tid+off]; __syncthreads(); }
  float var = red[0]*(1.f/512.f) - mu*mu; __syncthreads();
  float rs = rsqrtf(var + 1e-5f);
  yn[tid]     = (h1-mu)*rs*lng[tid] + lnb[tid];
  yn[tid+256] = (h2-mu)*rs*lng[tid+256] + lnb[tid+256];
  __syncthreads();
  float acc = b1[tid];
  #pragma unroll 8
  for (int k=0;k<512;++k) acc = fmaf(yn[k], W1[k*256+tid], acc);
  float y = fmaxf(acc, 0.f);
  red[tid] = y*W2[tid]; __syncthreads();
  for (int off=128; off; off>>=1){ if (tid<off) red[tid]+=red[tid+off]; __syncthreads(); }
  if (tid==0) out[b*24 + step] = red[0] + b2[0];
  if (step < NSTEP-1){
    __syncthreads();
    q_core(hl, WdT, ab, q + b*512);   // hl still holds h_new
  }
}

extern "C" void kernel_launch(void* const* d_in, const int* in_sizes, int n_in,
                              void* d_out, int out_size, void* d_ws, size_t ws_size,
                              hipStream_t stream){
  (void)in_sizes; (void)n_in; (void)out_size; (void)ws_size;
  const float* enc = (const float*)d_in[0];
  const float* h0  = (const float*)d_in[1];
  const float* We  = (const float*)d_in[2];
  const float* Wd  = (const float*)d_in[3];
  const float* ab  = (const float*)d_in[4];
  const float* av  = (const float*)d_in[5];
  const float* Wih = (const float*)d_in[6];
  const float* Whh = (const float*)d_in[7];
  const float* bih = (const float*)d_in[8];
  const float* bhh = (const float*)d_in[9];
  const float* lng = (const float*)d_in[10];
  const float* lnb = (const float*)d_in[11];
  const float* W1  = (const float*)d_in[12];
  const float* b1  = (const float*)d_in[13];
  const float* W2  = (const float*)d_in[14];
  const float* b2  = (const float*)d_in[15];
  float* out = (float*)d_out;
  char* ws = (char*)d_ws;
  u16*  ep   = (u16*)(ws + 0);          // 33,554,432
  u16*  encB = (u16*)(ws + 33554432);   // 33,554,432
  u16*  WeT  = (u16*)(ws + 67108864);   //    524,288
  u16*  WdT  = (u16*)(ws + 67633152);   //    524,288
  u16*  WihB = (u16*)(ws + 68157440);   //  3,145,728
  u16*  WhhB = (u16*)(ws + 71303168);   //  1,572,864
  float* hf  = (float*)(ws + 72876032); //    131,072
  u16*  xcat = (u16*)(ws + 73007104);   //    131,072  [ctx(512); h(512)] bf16 per b
  float* q   = (float*)(ws + 73138176); //    131,072
  float* sc  = (float*)(ws + 73269248); //    131,072
  float* gi  = (float*)(ws + 73400320); //    393,216
  float* gh  = (float*)(ws + 73793536); //    393,216  -> total ~70.8 MB

  k_cvt<<<16384, 256, 0, stream>>>(enc, encB, 16777216);
  k_cvt<<<1536, 256, 0, stream>>>(Wih, WihB, 1572864);
  k_cvt<<<768, 256, 0, stream>>>(Whh, WhhB, 786432);
  k_transpose512<<<dim3(16,16), dim3(32,8), 0, stream>>>(We, WeT);
  k_transpose512<<<dim3(16,16), dim3(32,8), 0, stream>>>(Wd, WdT);
  k_init<<<128, 256, 0, stream>>>(h0, hf, xcat);
  k_encproj<<<dim3(256,4), 256, 0, stream>>>(encB, WeT, ep);
  k_q0<<<64, 256, 0, stream>>>(hf, WdT, ab, q);
  for (int t=0; t<NSTEP; ++t){
    k_score<<<dim3(32,64), 256, 0, stream>>>(ep, q, av, sc);
    k_softctx<<<64, 512, 0, stream>>>(sc, encB, xcat);
    k_gru_gemm<<<dim3(24,2), 256, 0, stream>>>(xcat, WihB, bih, WhhB, bhh, gi, gh);
    k_fin<<<64, 256, 0, stream>>>(gi, gh, lng, lnb, W1, b1, W2, b2, WdT, ab,
                                  hf, xcat, q, out, t);
  }
}